// Round 1
// baseline (12654.104 us; speedup 1.0000x reference)
//
#include <hip/hip_runtime.h>
#include <hip/hip_bf16.h>

#define DD 512   // feature dim
#define SS 512   // NUM_SEG upper bound; use ix directly as segment id
#define RB 32    // rows staged per chunk in k_seg_gemm

// ---------------- counting sort of n by segment ----------------

__global__ void k_hist(const int* __restrict__ ix, int* __restrict__ count, int N) {
    int i = blockIdx.x * blockDim.x + threadIdx.x;
    if (i < N) atomicAdd(&count[ix[i]], 1);
}

// 1 block, SS threads: exclusive scan (serial in LDS by t0 — 512 entries, trivial)
__global__ void k_scan(const int* __restrict__ count, int* __restrict__ start,
                       int* __restrict__ cursor) {
    __shared__ int c[SS];
    __shared__ int o[SS + 1];
    int t = threadIdx.x;
    c[t] = count[t];
    __syncthreads();
    if (t == 0) {
        int a = 0;
        for (int s = 0; s < SS; s++) { o[s] = a; a += c[s]; }
        o[SS] = a;
    }
    __syncthreads();
    start[t] = o[t];
    cursor[t] = o[t];
    if (t == 0) start[SS] = o[SS];
}

__global__ void k_scatter(const int* __restrict__ ix, int* __restrict__ cursor,
                          int* __restrict__ sorted, int N) {
    int i = blockIdx.x * blockDim.x + threadIdx.x;
    if (i < N) {
        int pos = atomicAdd(&cursor[ix[i]], 1);
        sorted[pos] = i;
    }
}

// ---------------- fused f/g GEMM + softmax-weighted segment reduction ----------------
// grid (SS, B), 256 threads. Block (s,b) computes y[s][b][0..511].
// Thread t owns output dims e0=t and e1=t+256; accumulates den=sum(exp(g)),
// yn=sum((f)*exp(g)) over the segment's rows, in registers. No atomics.
__launch_bounds__(256, 2)
__global__ void k_seg_gemm(const float* __restrict__ x,
                           const float* __restrict__ Wf, const float* __restrict__ bf,
                           const float* __restrict__ Wg, const float* __restrict__ bg,
                           const int* __restrict__ sorted, const int* __restrict__ start,
                           float* __restrict__ y, int N, int B) {
    int s = blockIdx.x, b = blockIdx.y;
    int beg = start[s];
    int cnt = start[s + 1] - beg;
    int t = threadIdx.x;

    __shared__ float X[RB][DD];   // 64 KB -> 2 blocks/CU

    float den0 = 0.f, yn0 = 0.f, den1 = 0.f, yn1 = 0.f;
    const float* xb = x + (size_t)b * N * DD;

    for (int c0 = 0; c0 < cnt; c0 += RB) {
        int valid = min(RB, cnt - c0);
        __syncthreads();
        // stage up to RB rows of x (gathered via sorted order), float4-coalesced
        for (int i = t; i < RB * (DD / 4); i += 256) {
            int r = i >> 7, d4 = i & 127;
            float4 v = make_float4(0.f, 0.f, 0.f, 0.f);
            if (r < valid) {
                int n = sorted[beg + c0 + r];
                v = ((const float4*)(xb + (size_t)n * DD))[d4];
            }
            ((float4*)X[r])[d4] = v;
        }
        __syncthreads();

        #pragma unroll
        for (int ee = 0; ee < 2; ee++) {
            int e = ee ? (t + 256) : t;
            const float4* wg4 = (const float4*)(Wg + (size_t)e * DD);
            const float4* wf4 = (const float4*)(Wf + (size_t)e * DD);
            float g[RB], f[RB];
            #pragma unroll
            for (int r = 0; r < RB; r++) { g[r] = 0.f; f[r] = 0.f; }
            for (int d4 = 0; d4 < DD / 4; d4++) {
                float4 wg = wg4[d4], wf = wf4[d4];
                #pragma unroll
                for (int r = 0; r < RB; r++) {
                    float4 xv = ((const float4*)X[r])[d4];
                    g[r] = fmaf(xv.x, wg.x, g[r]);
                    g[r] = fmaf(xv.y, wg.y, g[r]);
                    g[r] = fmaf(xv.z, wg.z, g[r]);
                    g[r] = fmaf(xv.w, wg.w, g[r]);
                    f[r] = fmaf(xv.x, wf.x, f[r]);
                    f[r] = fmaf(xv.y, wf.y, f[r]);
                    f[r] = fmaf(xv.z, wf.z, f[r]);
                    f[r] = fmaf(xv.w, wf.w, f[r]);
                }
            }
            float bge = bg[e], bfe = bf[e];
            float den = 0.f, yn = 0.f;
            #pragma unroll
            for (int r = 0; r < RB; r++) {
                if (r < valid) {
                    float ex = __expf(g[r] + bge);
                    den += ex;
                    yn = fmaf(f[r] + bfe, ex, yn);
                }
            }
            if (ee == 0) { den0 += den; yn0 += yn; }
            else         { den1 += den; yn1 += yn; }
        }
    }

    size_t ybase = ((size_t)s * B + b) * DD;
    y[ybase + t]       = (cnt > 0) ? (yn0 / den0) : 0.f;
    y[ybase + t + 256] = (cnt > 0) ? (yn1 / den1) : 0.f;
}

// ---------------- hy = y @ Wh^T + bh (tiny GEMM: 4096 x 512 x 512) ----------------
// grid SS, 256 threads; block s stages y[s][0..7][.] (16 KB) and computes all 8 b.
__global__ void k_hy(const float* __restrict__ y, const float* __restrict__ Wh,
                     const float* __restrict__ bh, float* __restrict__ hy, int B) {
    int s = blockIdx.x, t = threadIdx.x;
    __shared__ float Ys[8][DD];  // B == 8
    const float4* ysrc = (const float4*)(y + (size_t)s * B * DD);
    for (int i = t; i < B * (DD / 4); i += 256)
        ((float4*)&Ys[0][0])[i] = ysrc[i];
    __syncthreads();

    int e0 = t, e1 = t + 256;
    const float4* w0 = (const float4*)(Wh + (size_t)e0 * DD);
    const float4* w1 = (const float4*)(Wh + (size_t)e1 * DD);
    float h0[8], h1[8];
    #pragma unroll
    for (int b = 0; b < 8; b++) { h0[b] = 0.f; h1[b] = 0.f; }
    for (int d4 = 0; d4 < DD / 4; d4++) {
        float4 a = w0[d4], c = w1[d4];
        #pragma unroll
        for (int b = 0; b < 8; b++) {
            float4 yv = ((const float4*)Ys[b])[d4];
            h0[b] = fmaf(yv.x, a.x, h0[b]); h0[b] = fmaf(yv.y, a.y, h0[b]);
            h0[b] = fmaf(yv.z, a.z, h0[b]); h0[b] = fmaf(yv.w, a.w, h0[b]);
            h1[b] = fmaf(yv.x, c.x, h1[b]); h1[b] = fmaf(yv.y, c.y, h1[b]);
            h1[b] = fmaf(yv.z, c.z, h1[b]); h1[b] = fmaf(yv.w, c.w, h1[b]);
        }
    }
    float bh0 = bh[e0], bh1 = bh[e1];
    #pragma unroll
    for (int b = 0; b < 8; b++) {
        hy[((size_t)s * B + b) * DD + e0] = h0[b] + bh0;
        hy[((size_t)s * B + b) * DD + e1] = h1[b] + bh1;
    }
}

// ---------------- out[b][n][:] = hy[ix[n]][b][:] (1 GiB coalesced write) ----------------
// 4 rows per 256-thread block: one wave per row, 2 float4 per lane.
__global__ void k_gather(const float* __restrict__ hy, const int* __restrict__ ix,
                         float* __restrict__ out, int N, int B) {
    int t = threadIdx.x;
    int j = t >> 6, lane = t & 63;
    int rowid = blockIdx.x * 4 + j;            // rowid = b*N + n, < 524288
    int b = rowid / N;
    int n = rowid - b * N;
    int s = ix[n];
    const float4* src = (const float4*)(hy + ((size_t)s * B + b) * DD);
    float4* dst = (float4*)(out + (size_t)rowid * DD);
    dst[lane]      = src[lane];
    dst[lane + 64] = src[lane + 64];
}

extern "C" void kernel_launch(void* const* d_in, const int* in_sizes, int n_in,
                              void* d_out, int out_size, void* d_ws, size_t ws_size,
                              hipStream_t stream) {
    const float* x  = (const float*)d_in[0];
    const int*   ix = (const int*)d_in[1];
    const float* Wf = (const float*)d_in[2];
    const float* bf = (const float*)d_in[3];
    const float* Wg = (const float*)d_in[4];
    const float* bg = (const float*)d_in[5];
    const float* Wh = (const float*)d_in[6];
    const float* bh = (const float*)d_in[7];
    float* out = (float*)d_out;

    int N = in_sizes[1];                 // 65536
    int D = in_sizes[3];                 // 512
    int B = in_sizes[0] / (N * D);       // 8
    int S = SS;                          // 512

    // ws layout: y[S*B*D] f32 | hy[S*B*D] f32 | count[S] | start[S+1] | cursor[S] | sorted[N]
    float* y      = (float*)d_ws;
    float* hy     = y + (size_t)S * B * D;
    int*   count  = (int*)(hy + (size_t)S * B * D);
    int*   startp = count + S;
    int*   cursor = startp + S + 1;
    int*   sorted = cursor + S;

    hipMemsetAsync(count, 0, S * sizeof(int), stream);
    k_hist<<<(N + 255) / 256, 256, 0, stream>>>(ix, count, N);
    k_scan<<<1, SS, 0, stream>>>(count, startp, cursor);
    k_scatter<<<(N + 255) / 256, 256, 0, stream>>>(ix, cursor, sorted, N);

    dim3 g4(S, B);
    k_seg_gemm<<<g4, 256, 0, stream>>>(x, Wf, bf, Wg, bg, sorted, startp, y, N, B);
    k_hy<<<S, 256, 0, stream>>>(y, Wh, bh, hy, B);
    k_gather<<<(B * N) / 4, 256, 0, stream>>>(hy, ix, out, N, B);
}